// Round 1
// baseline (2321.287 us; speedup 1.0000x reference)
//
#include <hip/hip_runtime.h>
#include <math.h>

#define NNODE 10000
#define NEDGE 160000
#define BATCH 64
#define KDIM  512   // inner dim of the two big GEMMs

// ---------------- graph build ----------------

__global__ void k_init_counts(int* counts) {
  int i = blockIdx.x * 256 + threadIdx.x;
  if (i < NNODE) counts[i] = 1;   // self-loop
}

__global__ void k_count(const int* __restrict__ ei, int* counts) {
  int e = blockIdx.x * 256 + threadIdx.x;
  if (e < NEDGE) atomicAdd(&counts[ei[NEDGE + e]], 1);  // dst row
}

__global__ __launch_bounds__(1024) void k_scan(const int* __restrict__ counts,
                                               int* offs, int* cursor, float* dinv) {
  __shared__ int sd[1024];
  int t = threadIdx.x;
  int b0 = t * 10, b1 = b0 + 10;
  if (b1 > NNODE) b1 = NNODE;
  if (b0 > NNODE) b0 = NNODE;
  int s = 0;
  for (int i = b0; i < b1; i++) s += counts[i];
  sd[t] = s;
  __syncthreads();
  for (int off = 1; off < 1024; off <<= 1) {
    int v = (t >= off) ? sd[t - off] : 0;
    __syncthreads();
    sd[t] += v;
    __syncthreads();
  }
  int excl = (t == 0) ? 0 : sd[t - 1];
  for (int i = b0; i < b1; i++) {
    offs[i] = excl;
    cursor[i] = excl;
    dinv[i] = rsqrtf((float)counts[i]);
    excl += counts[i];
  }
  if (t == 1023) offs[NNODE] = sd[1023];
}

__global__ void k_fill(const int* __restrict__ ei, const float* __restrict__ dinv,
                       int* cursor, int* srcn, float* wnorm) {
  int e = blockIdx.x * 256 + threadIdx.x;
  if (e >= NEDGE + NNODE) return;
  int s, d;
  if (e < NEDGE) { s = ei[e]; d = ei[NEDGE + e]; }
  else           { s = e - NEDGE; d = s; }
  int pos = atomicAdd(&cursor[d], 1);
  srcn[pos] = s;
  wnorm[pos] = dinv[s] * dinv[d];
}

// ---------------- mlp2: net1 = tanh(net @ W_mlp2), [64,640]@[640,1024] ----------------

__global__ __launch_bounds__(256) void k_mlp2(const float* __restrict__ net,
                                              const float* __restrict__ W,
                                              float* __restrict__ net1) {
  __shared__ float a[640];
  int b = blockIdx.x, t = threadIdx.x;
  for (int i = t; i < 640; i += 256) a[i] = net[b * 640 + i];
  __syncthreads();
  float acc0 = 0.f, acc1 = 0.f, acc2 = 0.f, acc3 = 0.f;
  for (int k = 0; k < 640; k++) {
    float av = a[k];
    const float* Wr = W + k * 1024 + t;
    acc0 += av * Wr[0];
    acc1 += av * Wr[256];
    acc2 += av * Wr[512];
    acc3 += av * Wr[768];
  }
  float* o = net1 + b * 1024 + t;
  o[0]   = tanhf(acc0);
  o[256] = tanhf(acc1);
  o[512] = tanhf(acc2);
  o[768] = tanhf(acc3);
}

// ------------- big GEMM: H[n*64+b][c] = tanh(sum_k A[b,k] * W[k, n*C+c]) -------------
// A = net1 (+ column offset), lda=1024. Block: 256 thr = 64 tx (cols) x 4 ty (row groups).
// Tile: all 64 rows x 128 cols. A chunk staged in LDS (broadcast reads across tx).

template <int C>
__global__ __launch_bounds__(256) void k_gemm(const float* __restrict__ A,
                                              const float* __restrict__ W,
                                              float* __restrict__ H, int NC) {
  __shared__ float As[64][68];  // +4 pad keeps float4 rows 16B aligned
  int tx = threadIdx.x & 63, ty = threadIdx.x >> 6;
  int c0 = blockIdx.x * 128;
  int cA = c0 + tx, cB = cA + 64;
  int ca = min(cA, NC - 1), cb = min(cB, NC - 1);
  float acc0[16], acc1[16];
#pragma unroll
  for (int i = 0; i < 16; i++) { acc0[i] = 0.f; acc1[i] = 0.f; }

  for (int kc = 0; kc < KDIM; kc += 64) {
    __syncthreads();
#pragma unroll
    for (int q = 0; q < 16; q++) {
      int idx = q * 256 + threadIdx.x;
      int r = idx >> 6, kk = idx & 63;
      As[r][kk] = A[r * 1024 + kc + kk];
    }
    __syncthreads();
#pragma unroll
    for (int k = 0; k < 64; k += 4) {
      const float* W0 = W + (size_t)(kc + k) * NC;
      float wa0 = W0[ca],          wb0 = W0[cb];
      float wa1 = W0[NC + ca],     wb1 = W0[NC + cb];
      float wa2 = W0[2 * NC + ca], wb2 = W0[2 * NC + cb];
      float wa3 = W0[3 * NC + ca], wb3 = W0[3 * NC + cb];
#pragma unroll
      for (int i = 0; i < 16; i++) {
        int r = ty + 4 * i;
        const float4 av = *(const float4*)&As[r][k];
        acc0[i] += av.x * wa0 + av.y * wa1 + av.z * wa2 + av.w * wa3;
        acc1[i] += av.x * wb0 + av.y * wb1 + av.z * wb2 + av.w * wb3;
      }
    }
  }
  if (cA < NC) {
    int n = cA / C, c = cA - n * C;
    float* Hp = H + (size_t)n * 64 * C + c;
#pragma unroll
    for (int i = 0; i < 16; i++) Hp[(ty + 4 * i) * C] = tanhf(acc0[i]);
  }
  if (cB < NC) {
    int n = cB / C, c = cB - n * C;
    float* Hp = H + (size_t)n * 64 * C + c;
#pragma unroll
    for (int i = 0; i < 16; i++) Hp[(ty + 4 * i) * C] = tanhf(acc1[i]);
  }
}

// ---------------- per-node CxC transform: y = x @ Wc ----------------

template <int C>
__global__ void k_transform(const float* __restrict__ x, const float* __restrict__ Wc,
                            float* __restrict__ y) {
  int idx = blockIdx.x * 256 + threadIdx.x;
  if (idx >= NNODE * BATCH) return;
  float xi[C];
  const float* xp = x + (size_t)idx * C;
#pragma unroll
  for (int c = 0; c < C; c++) xi[c] = xp[c];
  float* yp = y + (size_t)idx * C;
#pragma unroll
  for (int d = 0; d < C; d++) {
    float s = 0.f;
#pragma unroll
    for (int c = 0; c < C; c++) s += xi[c] * Wc[c * C + d];
    yp[d] = s;
  }
}

// ---------------- gather GCN: out[n,b,c] = bias[c] + sum_e wnorm*h[src,b,c] ----------------
// block = 64*C threads, one block per dst node. mode 0: tanh -> scratch [N,B,C]
// mode 1: *scale -> d_out[b, n, outc0+c]

__global__ void k_gather(const float* __restrict__ h, const int* __restrict__ offs,
                         const int* __restrict__ srcn, const float* __restrict__ wn,
                         const float* __restrict__ bias, float* __restrict__ out,
                         int C, int mode, float scale, int outc0) {
  int n = blockIdx.x, t = threadIdx.x;
  int BC = blockDim.x;
  int beg = offs[n], end = offs[n + 1];
  float acc = 0.f;
  int k = beg;
  for (; k + 2 <= end; k += 2) {
    int s0 = srcn[k], s1 = srcn[k + 1];
    float w0 = wn[k], w1 = wn[k + 1];
    acc += w0 * h[(size_t)s0 * BC + t];
    acc += w1 * h[(size_t)s1 * BC + t];
  }
  if (k < end) acc += wn[k] * h[(size_t)srcn[k] * BC + t];
  int b = t / C, c = t - b * C;
  acc += bias[c];
  if (mode == 0) {
    out[(size_t)n * BC + t] = tanhf(acc);
  } else {
    out[(size_t)b * (NNODE * 9) + n * 9 + outc0 + c] = acc * scale;
  }
}

// ---------------- launch ----------------

extern "C" void kernel_launch(void* const* d_in, const int* in_sizes, int n_in,
                              void* d_out, int out_size, void* d_ws, size_t ws_size,
                              hipStream_t stream) {
  const float* net     = (const float*)d_in[0];
  const int*   ei      = (const int*)d_in[1];
  const float* W_mlp2  = (const float*)d_in[2];
  const float* W_logr  = (const float*)d_in[3];
  const float* W_s     = (const float*)d_in[4];
  const float* W1_logr = (const float*)d_in[5];
  const float* b1_logr = (const float*)d_in[6];
  const float* W1_s    = (const float*)d_in[7];
  const float* b1_s    = (const float*)d_in[8];
  const float* W4_s    = (const float*)d_in[9];
  const float* b4_s    = (const float*)d_in[10];
  float* out = (float*)d_out;

  char* w = (char*)d_ws;
  auto carve = [&](size_t nbytes) {
    char* p = w;
    w += (nbytes + 255) & ~(size_t)255;
    return p;
  };
  int*   counts = (int*)  carve(NNODE * 4);
  int*   offs   = (int*)  carve((NNODE + 1) * 4);
  int*   cursor = (int*)  carve(NNODE * 4);
  float* dinv   = (float*)carve(NNODE * 4);
  int*   srcn   = (int*)  carve((NEDGE + NNODE) * 4);
  float* wnorm  = (float*)carve((NEDGE + NNODE) * 4);
  float* net1   = (float*)carve(BATCH * 1024 * 4);
  float* Hlogr  = (float*)carve((size_t)NNODE * BATCH * 3 * 4);
  float* hA     = (float*)carve((size_t)NNODE * BATCH * 3 * 4);
  float* Hs     = (float*)carve((size_t)NNODE * BATCH * 6 * 4);
  float* hB     = (float*)carve((size_t)NNODE * BATCH * 6 * 4);
  float* tmid   = Hlogr;  // aliases Hlogr+hA region (both dead by then; 2*1.92M = 3.84M floats)
  float* hC     = hB;     // hB dead after mid gather

  // graph
  k_init_counts<<<(NNODE + 255) / 256, 256, 0, stream>>>(counts);
  k_count<<<(NEDGE + 255) / 256, 256, 0, stream>>>(ei, counts);
  k_scan<<<1, 1024, 0, stream>>>(counts, offs, cursor, dinv);
  k_fill<<<(NEDGE + NNODE + 255) / 256, 256, 0, stream>>>(ei, dinv, cursor, srcn, wnorm);

  // dense front-end
  k_mlp2<<<BATCH, 256, 0, stream>>>(net, W_mlp2, net1);
  k_gemm<3><<<(30000 + 127) / 128, 256, 0, stream>>>(net1,       W_logr, Hlogr, 30000);
  k_gemm<6><<<(60000 + 127) / 128, 256, 0, stream>>>(net1 + 512, W_s,    Hs,    60000);

  // GCN logr (layer 1, output *4 to out[...,0:3])
  k_transform<3><<<(NNODE * BATCH + 255) / 256, 256, 0, stream>>>(Hlogr, W1_logr, hA);
  k_gather<<<NNODE, 64 * 3, 0, stream>>>(hA, offs, srcn, wnorm, b1_logr, out, 3, 1, 4.0f, 0);

  // GCN s layer 1 (tanh -> tmid)
  k_transform<6><<<(NNODE * BATCH + 255) / 256, 256, 0, stream>>>(Hs, W1_s, hB);
  k_gather<<<NNODE, 64 * 6, 0, stream>>>(hB, offs, srcn, wnorm, b1_s, tmid, 6, 0, 1.0f, 0);

  // GCN s layer 4 (output *50 to out[...,3:9])
  k_transform<6><<<(NNODE * BATCH + 255) / 256, 256, 0, stream>>>(tmid, W4_s, hC);
  k_gather<<<NNODE, 64 * 6, 0, stream>>>(hC, offs, srcn, wnorm, b4_s, out, 6, 1, 50.0f, 3);
}

// Round 2
// 1119.742 us; speedup vs baseline: 2.0731x; 2.0731x over previous
//
#include <hip/hip_runtime.h>
#include <math.h>

#define NNODE 10000
#define NEDGE 160000
#define BATCH 64
#define KDIM  512   // inner dim of the two big GEMMs

// ---------------- graph build ----------------

__global__ void k_init_counts(int* counts) {
  int i = blockIdx.x * 256 + threadIdx.x;
  if (i < NNODE) counts[i] = 1;   // self-loop
}

__global__ void k_count(const int* __restrict__ ei, int* counts) {
  int e = blockIdx.x * 256 + threadIdx.x;
  if (e < NEDGE) atomicAdd(&counts[ei[NEDGE + e]], 1);  // dst row
}

__global__ __launch_bounds__(1024) void k_scan(const int* __restrict__ counts,
                                               int* offs, int* cursor, float* dinv) {
  __shared__ int sd[1024];
  int t = threadIdx.x;
  int b0 = t * 10, b1 = b0 + 10;
  if (b1 > NNODE) b1 = NNODE;
  if (b0 > NNODE) b0 = NNODE;
  int s = 0;
  for (int i = b0; i < b1; i++) s += counts[i];
  sd[t] = s;
  __syncthreads();
  for (int off = 1; off < 1024; off <<= 1) {
    int v = (t >= off) ? sd[t - off] : 0;
    __syncthreads();
    sd[t] += v;
    __syncthreads();
  }
  int excl = (t == 0) ? 0 : sd[t - 1];
  for (int i = b0; i < b1; i++) {
    offs[i] = excl;
    cursor[i] = excl;
    dinv[i] = rsqrtf((float)counts[i]);
    excl += counts[i];
  }
  if (t == 1023) offs[NNODE] = sd[1023];
}

__global__ void k_fill(const int* __restrict__ ei, const float* __restrict__ dinv,
                       int* cursor, int* srcn, float* wnorm) {
  int e = blockIdx.x * 256 + threadIdx.x;
  if (e >= NEDGE + NNODE) return;
  int s, d;
  if (e < NEDGE) { s = ei[e]; d = ei[NEDGE + e]; }
  else           { s = e - NEDGE; d = s; }
  int pos = atomicAdd(&cursor[d], 1);
  srcn[pos] = s;
  wnorm[pos] = dinv[s] * dinv[d];
}

// ---------------- mlp2: net1 = tanh(net @ W_mlp2), [64,640]@[640,1024] ----------------

__global__ __launch_bounds__(256) void k_mlp2(const float* __restrict__ net,
                                              const float* __restrict__ W,
                                              float* __restrict__ net1) {
  __shared__ float a[640];
  int b = blockIdx.x, t = threadIdx.x;
  for (int i = t; i < 640; i += 256) a[i] = net[b * 640 + i];
  __syncthreads();
  float acc0 = 0.f, acc1 = 0.f, acc2 = 0.f, acc3 = 0.f;
  for (int k = 0; k < 640; k++) {
    float av = a[k];
    const float* Wr = W + k * 1024 + t;
    acc0 += av * Wr[0];
    acc1 += av * Wr[256];
    acc2 += av * Wr[512];
    acc3 += av * Wr[768];
  }
  float* o = net1 + b * 1024 + t;
  o[0]   = tanhf(acc0);
  o[256] = tanhf(acc1);
  o[512] = tanhf(acc2);
  o[768] = tanhf(acc3);
}

// ------------- big GEMM: H[(n*64+b)*C + c] = tanh(sum_k A[b,k] * W[k, n*C+c]) -------------
// Tile: 64 rows x 96 cols (96 % C == 0 so each block owns a CONTIGUOUS H region).
// 192 threads: tx = tid%96 owns one column, ty = tid/96 owns a 32-row half.
// Epilogue stages the tile in padded LDS (H-flat order) -> coalesced float4 writes.

template <int C>
__global__ __launch_bounds__(192) void k_gemm(const float* __restrict__ A,
                                              const float* __restrict__ W,
                                              float* __restrict__ H, int NC) {
  constexpr int NODE_F = 64 * C;        // floats per node chunk of H
  constexpr int NODE_P = NODE_F + 4;    // padded LDS stride (keeps 16B align, spreads banks)
  constexpr int NTILE  = 96 / C;        // nodes per tile
  constexpr int LDSF   = (NTILE * NODE_P > 64 * 68) ? NTILE * NODE_P : 64 * 68;
  __shared__ float lds[LDSF];
  float* As = lds;                      // [64][68] during the k-loop

  int tid = threadIdx.x;
  int tx = tid % 96, ty = tid / 96;     // column, row-half
  int c0 = blockIdx.x * 96;
  int col = c0 + tx;
  int cc = min(col, NC - 1);

  float acc[32];
#pragma unroll
  for (int i = 0; i < 32; i++) acc[i] = 0.f;

  for (int kc = 0; kc < KDIM; kc += 64) {
    __syncthreads();
    for (int idx = tid; idx < 64 * 64; idx += 192) {
      int r = idx >> 6, kk = idx & 63;
      As[r * 68 + kk] = A[r * 1024 + kc + kk];
    }
    __syncthreads();
#pragma unroll
    for (int k = 0; k < 64; k += 4) {
      const float* Wp = W + (size_t)(kc + k) * NC + cc;
      float w0 = Wp[0], w1 = Wp[NC], w2 = Wp[2 * NC], w3 = Wp[3 * NC];
#pragma unroll
      for (int i = 0; i < 32; i++) {
        int r = ty * 32 + i;
        const float4 av = *(const float4*)&As[r * 68 + k];
        acc[i] += av.x * w0 + av.y * w1 + av.z * w2 + av.w * w3;
      }
    }
  }
  __syncthreads();  // As dead; reuse lds as the output tile

  int nact = min(96, NC - c0);          // active cols this block (multiple of C)
  if (tx < nact) {
    int nl = tx / C, ccl = tx % C;
    float* lp = lds + nl * NODE_P + ccl;
#pragma unroll
    for (int i = 0; i < 32; i++) {
      int b = ty * 32 + i;
      lp[b * C] = tanhf(acc[i]);
    }
  }
  __syncthreads();

  int region = nact * 64;               // floats in this block's contiguous H span
  float* Hb = H + (size_t)c0 * 64;      // == (c0/C) * 64 * C
  for (int f = tid * 4; f < region; f += 192 * 4) {
    int n = f / NODE_F, rem = f - n * NODE_F;
    const float4 v = *(const float4*)&lds[n * NODE_P + rem];
    *(float4*)&Hb[f] = v;
  }
}

// ---------------- per-node CxC transform: y = x @ Wc ----------------

template <int C>
__global__ void k_transform(const float* __restrict__ x, const float* __restrict__ Wc,
                            float* __restrict__ y) {
  int idx = blockIdx.x * 256 + threadIdx.x;
  if (idx >= NNODE * BATCH) return;
  float xi[C];
  const float* xp = x + (size_t)idx * C;
#pragma unroll
  for (int c = 0; c < C; c++) xi[c] = xp[c];
  float* yp = y + (size_t)idx * C;
#pragma unroll
  for (int d = 0; d < C; d++) {
    float s = 0.f;
#pragma unroll
    for (int c = 0; c < C; c++) s += xi[c] * Wc[c * C + d];
    yp[d] = s;
  }
}

// ---------------- gather GCN: out[n,b,c] = bias[c] + sum_e wnorm*h[src,b,c] ----------------
// block = 64*C threads, one block per dst node. mode 0: tanh -> scratch [N,B,C]
// mode 1: *scale -> d_out[b, n, outc0+c]

__global__ void k_gather(const float* __restrict__ h, const int* __restrict__ offs,
                         const int* __restrict__ srcn, const float* __restrict__ wn,
                         const float* __restrict__ bias, float* __restrict__ out,
                         int C, int mode, float scale, int outc0) {
  int n = blockIdx.x, t = threadIdx.x;
  int BC = blockDim.x;
  int beg = offs[n], end = offs[n + 1];
  float acc = 0.f;
  int k = beg;
  for (; k + 2 <= end; k += 2) {
    int s0 = srcn[k], s1 = srcn[k + 1];
    float w0 = wn[k], w1 = wn[k + 1];
    acc += w0 * h[(size_t)s0 * BC + t];
    acc += w1 * h[(size_t)s1 * BC + t];
  }
  if (k < end) acc += wn[k] * h[(size_t)srcn[k] * BC + t];
  int b = t / C, c = t - b * C;
  acc += bias[c];
  if (mode == 0) {
    out[(size_t)n * BC + t] = tanhf(acc);
  } else {
    out[(size_t)b * (NNODE * 9) + n * 9 + outc0 + c] = acc * scale;
  }
}

// ---------------- launch ----------------

extern "C" void kernel_launch(void* const* d_in, const int* in_sizes, int n_in,
                              void* d_out, int out_size, void* d_ws, size_t ws_size,
                              hipStream_t stream) {
  const float* net     = (const float*)d_in[0];
  const int*   ei      = (const int*)d_in[1];
  const float* W_mlp2  = (const float*)d_in[2];
  const float* W_logr  = (const float*)d_in[3];
  const float* W_s     = (const float*)d_in[4];
  const float* W1_logr = (const float*)d_in[5];
  const float* b1_logr = (const float*)d_in[6];
  const float* W1_s    = (const float*)d_in[7];
  const float* b1_s    = (const float*)d_in[8];
  const float* W4_s    = (const float*)d_in[9];
  const float* b4_s    = (const float*)d_in[10];
  float* out = (float*)d_out;

  char* w = (char*)d_ws;
  auto carve = [&](size_t nbytes) {
    char* p = w;
    w += (nbytes + 255) & ~(size_t)255;
    return p;
  };
  int*   counts = (int*)  carve(NNODE * 4);
  int*   offs   = (int*)  carve((NNODE + 1) * 4);
  int*   cursor = (int*)  carve(NNODE * 4);
  float* dinv   = (float*)carve(NNODE * 4);
  int*   srcn   = (int*)  carve((NEDGE + NNODE) * 4);
  float* wnorm  = (float*)carve((NEDGE + NNODE) * 4);
  float* net1   = (float*)carve(BATCH * 1024 * 4);
  float* Hlogr  = (float*)carve((size_t)NNODE * BATCH * 3 * 4);
  float* hA     = (float*)carve((size_t)NNODE * BATCH * 3 * 4);
  float* Hs     = (float*)carve((size_t)NNODE * BATCH * 6 * 4);
  float* hB     = (float*)carve((size_t)NNODE * BATCH * 6 * 4);
  float* tmid   = Hlogr;  // aliases Hlogr+hA region (both dead by then)
  float* hC     = hB;     // hB dead after mid gather

  // graph
  k_init_counts<<<(NNODE + 255) / 256, 256, 0, stream>>>(counts);
  k_count<<<(NEDGE + 255) / 256, 256, 0, stream>>>(ei, counts);
  k_scan<<<1, 1024, 0, stream>>>(counts, offs, cursor, dinv);
  k_fill<<<(NEDGE + NNODE + 255) / 256, 256, 0, stream>>>(ei, dinv, cursor, srcn, wnorm);

  // dense front-end
  k_mlp2<<<BATCH, 256, 0, stream>>>(net, W_mlp2, net1);
  k_gemm<3><<<(30000 + 95) / 96, 192, 0, stream>>>(net1,       W_logr, Hlogr, 30000);
  k_gemm<6><<<(60000 + 95) / 96, 192, 0, stream>>>(net1 + 512, W_s,    Hs,    60000);

  // GCN logr (layer 1, output *4 to out[...,0:3])
  k_transform<3><<<(NNODE * BATCH + 255) / 256, 256, 0, stream>>>(Hlogr, W1_logr, hA);
  k_gather<<<NNODE, 64 * 3, 0, stream>>>(hA, offs, srcn, wnorm, b1_logr, out, 3, 1, 4.0f, 0);

  // GCN s layer 1 (tanh -> tmid)
  k_transform<6><<<(NNODE * BATCH + 255) / 256, 256, 0, stream>>>(Hs, W1_s, hB);
  k_gather<<<NNODE, 64 * 6, 0, stream>>>(hB, offs, srcn, wnorm, b1_s, tmid, 6, 0, 1.0f, 0);

  // GCN s layer 4 (output *50 to out[...,3:9])
  k_transform<6><<<(NNODE * BATCH + 255) / 256, 256, 0, stream>>>(tmid, W4_s, hC);
  k_gather<<<NNODE, 64 * 6, 0, stream>>>(hC, offs, srcn, wnorm, b4_s, out, 6, 1, 50.0f, 3);
}

// Round 3
// 675.999 us; speedup vs baseline: 3.4339x; 1.6564x over previous
//
#include <hip/hip_runtime.h>
#include <math.h>

#define NNODE 10000
#define NEDGE 160000
#define BATCH 64
#define KDIM  512   // inner dim of the two big GEMMs

// ---------------- graph build ----------------

__global__ void k_init_counts(int* counts) {
  int i = blockIdx.x * 256 + threadIdx.x;
  if (i < NNODE) counts[i] = 1;   // self-loop
}

__global__ void k_count(const int* __restrict__ ei, int* counts) {
  int e = blockIdx.x * 256 + threadIdx.x;
  if (e < NEDGE) atomicAdd(&counts[ei[NEDGE + e]], 1);  // dst row
}

__global__ __launch_bounds__(1024) void k_scan(const int* __restrict__ counts,
                                               int* offs, int* cursor, float* dinv) {
  __shared__ int sd[1024];
  int t = threadIdx.x;
  int b0 = t * 10, b1 = b0 + 10;
  if (b1 > NNODE) b1 = NNODE;
  if (b0 > NNODE) b0 = NNODE;
  int s = 0;
  for (int i = b0; i < b1; i++) s += counts[i];
  sd[t] = s;
  __syncthreads();
  for (int off = 1; off < 1024; off <<= 1) {
    int v = (t >= off) ? sd[t - off] : 0;
    __syncthreads();
    sd[t] += v;
    __syncthreads();
  }
  int excl = (t == 0) ? 0 : sd[t - 1];
  for (int i = b0; i < b1; i++) {
    offs[i] = excl;
    cursor[i] = excl;
    dinv[i] = rsqrtf((float)counts[i]);
    excl += counts[i];
  }
  if (t == 1023) offs[NNODE] = sd[1023];
}

__global__ void k_fill(const int* __restrict__ ei, const float* __restrict__ dinv,
                       int* cursor, int* srcn, float* wnorm) {
  int e = blockIdx.x * 256 + threadIdx.x;
  if (e >= NEDGE + NNODE) return;
  int s, d;
  if (e < NEDGE) { s = ei[e]; d = ei[NEDGE + e]; }
  else           { s = e - NEDGE; d = s; }
  int pos = atomicAdd(&cursor[d], 1);
  srcn[pos] = s;
  wnorm[pos] = dinv[s] * dinv[d];
}

// ---------------- mlp2: net1 = tanh(net @ W_mlp2), [64,640]@[640,1024] ----------------

__global__ __launch_bounds__(256) void k_mlp2(const float* __restrict__ net,
                                              const float* __restrict__ W,
                                              float* __restrict__ net1) {
  __shared__ float a[640];
  int b = blockIdx.x, t = threadIdx.x;
  for (int i = t; i < 640; i += 256) a[i] = net[b * 640 + i];
  __syncthreads();
  float acc0 = 0.f, acc1 = 0.f, acc2 = 0.f, acc3 = 0.f;
  for (int k = 0; k < 640; k++) {
    float av = a[k];
    const float* Wr = W + k * 1024 + t;
    acc0 += av * Wr[0];
    acc1 += av * Wr[256];
    acc2 += av * Wr[512];
    acc3 += av * Wr[768];
  }
  float* o = net1 + b * 1024 + t;
  o[0]   = tanhf(acc0);
  o[256] = tanhf(acc1);
  o[512] = tanhf(acc2);
  o[768] = tanhf(acc3);
}

// ------------- big GEMM: H[(n*64+b)*C + c] = tanh(sum_k A[b,k] * W[k, n*C+c]) -------------
// Tile: 64 rows x 96 cols. 192 threads = 24 col-threads (4 contiguous cols each, float4 W
// loads) x 8 row-threads (8 rows each, r = tr + 8*i so tr-groups land on distinct banks).
// Per 4-k step: 8 ds_read_b128 (A) + 4 float4 W loads -> 128 FMA (16 FMA / LDS read).
// Epilogue stages tanh'd tile in padded LDS in H-flat order -> coalesced float4 stores.

template <int C>
__global__ __launch_bounds__(192) void k_gemm(const float* __restrict__ A,
                                              const float* __restrict__ W,
                                              float* __restrict__ H, int NC) {
  constexpr int NODE_F = 64 * C;        // floats per node chunk of H
  constexpr int NODE_P = NODE_F + 4;    // padded LDS stride
  constexpr int NTILE  = 96 / C;        // nodes per tile
  constexpr int LDSA   = 64 * 68;
  constexpr int LDSF   = (NTILE * NODE_P > LDSA) ? NTILE * NODE_P : LDSA;
  __shared__ float lds[LDSF];
  float* As = lds;                      // [64][68] during the k-loop

  int tid = threadIdx.x;
  int tc = tid % 24, tr = tid / 24;     // col-thread, row-thread
  int c0 = blockIdx.x * 96;
  int cw = c0 + tc * 4;
  int cwc = min(cw, NC - 4);            // clamped, stays 16B-aligned (NC % 4 == 0)

  float acc[8][4];
#pragma unroll
  for (int i = 0; i < 8; i++)
#pragma unroll
    for (int j = 0; j < 4; j++) acc[i][j] = 0.f;

  for (int kc = 0; kc < KDIM; kc += 64) {
    __syncthreads();
    for (int idx = tid; idx < 64 * 64; idx += 192) {
      int r = idx >> 6, kk = idx & 63;
      As[r * 68 + kk] = A[r * 1024 + kc + kk];
    }
    __syncthreads();
#pragma unroll 2
    for (int k = 0; k < 64; k += 4) {
      const float* Wp = W + (size_t)(kc + k) * NC + cwc;
      float4 w0 = *(const float4*)(Wp);
      float4 w1 = *(const float4*)(Wp + NC);
      float4 w2 = *(const float4*)(Wp + 2 * (size_t)NC);
      float4 w3 = *(const float4*)(Wp + 3 * (size_t)NC);
#pragma unroll
      for (int i = 0; i < 8; i++) {
        const float4 av = *(const float4*)&As[(tr + 8 * i) * 68 + k];
        acc[i][0] += av.x * w0.x + av.y * w1.x + av.z * w2.x + av.w * w3.x;
        acc[i][1] += av.x * w0.y + av.y * w1.y + av.z * w2.y + av.w * w3.y;
        acc[i][2] += av.x * w0.z + av.y * w1.z + av.z * w2.z + av.w * w3.z;
        acc[i][3] += av.x * w0.w + av.y * w1.w + av.z * w2.w + av.w * w3.w;
      }
    }
  }
  __syncthreads();  // As dead; reuse lds as the output tile

  int nact = min(96, NC - c0);          // active cols this block (multiple of C)
#pragma unroll
  for (int j = 0; j < 4; j++) {
    int cl = tc * 4 + j;                // local col
    if (cl < nact) {
      int nl = cl / C, ccl = cl % C;
      float* lp = lds + nl * NODE_P + ccl;
#pragma unroll
      for (int i = 0; i < 8; i++) {
        int b = tr + 8 * i;
        lp[b * C] = tanhf(acc[i][j]);
      }
    }
  }
  __syncthreads();

  int region = nact * 64;               // floats in this block's contiguous H span
  float* Hb = H + (size_t)c0 * 64;      // == (c0/C) * 64 * C
  for (int f = tid * 4; f < region; f += 192 * 4) {
    int n = f / NODE_F, rem = f - n * NODE_F;
    const float4 v = *(const float4*)&lds[n * NODE_P + rem];
    *(float4*)&Hb[f] = v;
  }
}

// ---------------- per-node CxC transform: y = x @ Wc ----------------

template <int C>
__global__ void k_transform(const float* __restrict__ x, const float* __restrict__ Wc,
                            float* __restrict__ y) {
  int idx = blockIdx.x * 256 + threadIdx.x;
  if (idx >= NNODE * BATCH) return;
  float xi[C];
  const float* xp = x + (size_t)idx * C;
#pragma unroll
  for (int c = 0; c < C; c++) xi[c] = xp[c];
  float* yp = y + (size_t)idx * C;
#pragma unroll
  for (int d = 0; d < C; d++) {
    float s = 0.f;
#pragma unroll
    for (int c = 0; c < C; c++) s += xi[c] * Wc[c * C + d];
    yp[d] = s;
  }
}

// ---------------- gather GCN: out[n,b,c] = bias[c] + sum_e wnorm*h[src,b,c] ----------------
// block = 64*C threads, one block per dst node. mode 0: tanh -> scratch [N,B,C]
// mode 1: *scale -> d_out[b, n, outc0+c]

__global__ void k_gather(const float* __restrict__ h, const int* __restrict__ offs,
                         const int* __restrict__ srcn, const float* __restrict__ wn,
                         const float* __restrict__ bias, float* __restrict__ out,
                         int C, int mode, float scale, int outc0) {
  int n = blockIdx.x, t = threadIdx.x;
  int BC = blockDim.x;
  int beg = offs[n], end = offs[n + 1];
  float acc = 0.f;
  int k = beg;
  for (; k + 2 <= end; k += 2) {
    int s0 = srcn[k], s1 = srcn[k + 1];
    float w0 = wn[k], w1 = wn[k + 1];
    acc += w0 * h[(size_t)s0 * BC + t];
    acc += w1 * h[(size_t)s1 * BC + t];
  }
  if (k < end) acc += wn[k] * h[(size_t)srcn[k] * BC + t];
  int b = t / C, c = t - b * C;
  acc += bias[c];
  if (mode == 0) {
    out[(size_t)n * BC + t] = tanhf(acc);
  } else {
    out[(size_t)b * (NNODE * 9) + n * 9 + outc0 + c] = acc * scale;
  }
}

// ---------------- launch ----------------

extern "C" void kernel_launch(void* const* d_in, const int* in_sizes, int n_in,
                              void* d_out, int out_size, void* d_ws, size_t ws_size,
                              hipStream_t stream) {
  const float* net     = (const float*)d_in[0];
  const int*   ei      = (const int*)d_in[1];
  const float* W_mlp2  = (const float*)d_in[2];
  const float* W_logr  = (const float*)d_in[3];
  const float* W_s     = (const float*)d_in[4];
  const float* W1_logr = (const float*)d_in[5];
  const float* b1_logr = (const float*)d_in[6];
  const float* W1_s    = (const float*)d_in[7];
  const float* b1_s    = (const float*)d_in[8];
  const float* W4_s    = (const float*)d_in[9];
  const float* b4_s    = (const float*)d_in[10];
  float* out = (float*)d_out;

  char* w = (char*)d_ws;
  auto carve = [&](size_t nbytes) {
    char* p = w;
    w += (nbytes + 255) & ~(size_t)255;
    return p;
  };
  int*   counts = (int*)  carve(NNODE * 4);
  int*   offs   = (int*)  carve((NNODE + 1) * 4);
  int*   cursor = (int*)  carve(NNODE * 4);
  float* dinv   = (float*)carve(NNODE * 4);
  int*   srcn   = (int*)  carve((NEDGE + NNODE) * 4);
  float* wnorm  = (float*)carve((NEDGE + NNODE) * 4);
  float* net1   = (float*)carve(BATCH * 1024 * 4);
  float* Hlogr  = (float*)carve((size_t)NNODE * BATCH * 3 * 4);
  float* hA     = (float*)carve((size_t)NNODE * BATCH * 3 * 4);
  float* Hs     = (float*)carve((size_t)NNODE * BATCH * 6 * 4);
  float* hB     = (float*)carve((size_t)NNODE * BATCH * 6 * 4);
  float* tmid   = Hlogr;  // aliases Hlogr+hA region (both dead by then)
  float* hC     = hB;     // hB dead after mid gather

  // graph
  k_init_counts<<<(NNODE + 255) / 256, 256, 0, stream>>>(counts);
  k_count<<<(NEDGE + 255) / 256, 256, 0, stream>>>(ei, counts);
  k_scan<<<1, 1024, 0, stream>>>(counts, offs, cursor, dinv);
  k_fill<<<(NEDGE + NNODE + 255) / 256, 256, 0, stream>>>(ei, dinv, cursor, srcn, wnorm);

  // dense front-end
  k_mlp2<<<BATCH, 256, 0, stream>>>(net, W_mlp2, net1);
  k_gemm<3><<<(30000 + 95) / 96, 192, 0, stream>>>(net1,       W_logr, Hlogr, 30000);
  k_gemm<6><<<(60000 + 95) / 96, 192, 0, stream>>>(net1 + 512, W_s,    Hs,    60000);

  // GCN logr (layer 1, output *4 to out[...,0:3])
  k_transform<3><<<(NNODE * BATCH + 255) / 256, 256, 0, stream>>>(Hlogr, W1_logr, hA);
  k_gather<<<NNODE, 64 * 3, 0, stream>>>(hA, offs, srcn, wnorm, b1_logr, out, 3, 1, 4.0f, 0);

  // GCN s layer 1 (tanh -> tmid)
  k_transform<6><<<(NNODE * BATCH + 255) / 256, 256, 0, stream>>>(Hs, W1_s, hB);
  k_gather<<<NNODE, 64 * 6, 0, stream>>>(hB, offs, srcn, wnorm, b1_s, tmid, 6, 0, 1.0f, 0);

  // GCN s layer 4 (output *50 to out[...,3:9])
  k_transform<6><<<(NNODE * BATCH + 255) / 256, 256, 0, stream>>>(tmid, W4_s, hC);
  k_gather<<<NNODE, 64 * 6, 0, stream>>>(hC, offs, srcn, wnorm, b4_s, out, 6, 1, 50.0f, 3);
}